// Round 11
// baseline (273.678 us; speedup 1.0000x reference)
//
#include <hip/hip_runtime.h>

// MultiHeadedAttention: B=2, S=2048, D=1024, H=16, DH=64. fp32 in/out.
// R20: attn frozen at the R15 body (53.2us twice-measured; 5 perturbations
// all neutral/negative -- R16 spill, R17 wave-split +3us, R18 spill, R19
// V-dbuf +21us stall). Work moves to the ~185us non-attn bucket:
//  - gemm_qkv: BK=64 (two k-chunks per barrier pair): 64->32 barrier
//    drains, 8 async16 in flight, LDS 16->32KB (3 blocks/CU kept).
//  - gemm_final: Wo fp32->bf16 convert folded into B-staging (f32x4 loads +
//    cvt + ds_write_b128): convert_wo kernel + 4MB traffic removed.
//  - prep merged (R16), XCD-grouped GEMM grids (R18) kept.
#define B_ 2
#define S_ 2048
#define D_ 1024
#define H_ 16
#define DH_ 64

typedef float f32x4 __attribute__((ext_vector_type(4)));
typedef short s16x8 __attribute__((ext_vector_type(8)));
typedef __bf16 bf16x8 __attribute__((ext_vector_type(8)));
typedef unsigned int uint;

// ---- MFMA wrapper: tolerate either builtin signature (short8 or bf16x8) ----
template <typename T>
static __device__ auto mfma_sel(T a, T b, f32x4 c, int)
    -> decltype(__builtin_amdgcn_mfma_f32_16x16x32_bf16(a, b, c, 0, 0, 0)) {
  return __builtin_amdgcn_mfma_f32_16x16x32_bf16(a, b, c, 0, 0, 0);
}
template <typename T>
static __device__ f32x4 mfma_sel(T a, T b, f32x4 c, long) {
  return __builtin_amdgcn_mfma_f32_16x16x32_bf16(
      __builtin_bit_cast(bf16x8, a), __builtin_bit_cast(bf16x8, b), c, 0, 0, 0);
}
static __device__ __forceinline__ f32x4 mfma_bf16(s16x8 a, s16x8 b, f32x4 c) {
  return mfma_sel(a, b, c, 0);
}

static __device__ __forceinline__ short f2bf(float f) {
  unsigned u = __float_as_uint(f);
  u += 0x7fffu + ((u >> 16) & 1u);
  return (short)(u >> 16);
}

// hardware RNE convert (v_cvt_pk_bf16_f32) -- bit-identical to f2bf for
// non-NaN inputs.
static __device__ __forceinline__ short f2bf_rn(float f) {
  return __builtin_bit_cast(short, (__bf16)f);
}

// ---- async 16B global -> LDS (per-lane GLOBAL addr ok; LDS side = base+lane*16)
static __device__ __forceinline__ void async16(const short* g, short* l) {
  __builtin_amdgcn_global_load_lds(
      (const __attribute__((address_space(1))) unsigned int*)g,
      (__attribute__((address_space(3))) unsigned int*)l, 16, 0, 0);
}

// ---- merged prep: blocks [0,3584) fp32->bf16 fragment convert;
//      blocks [3584,4608) mask->bitmask with per-block inline dtype detect --
__global__ __launch_bounds__(256) void prep_kernel(
    const float* __restrict__ q, const float* __restrict__ wq,
    const float* __restrict__ wk, const float* __restrict__ wv,
    const void* __restrict__ mask, short* __restrict__ qbf,
    short* __restrict__ wqkv, uint* __restrict__ bmT) {
  __shared__ int s_gt1, s_notf;
  const int bid = blockIdx.x;
  const int t = threadIdx.x;

  if (bid < 3584) {
    // ---- convert part (unchanged math) ----
    const float* src;
    short* dst;
    int rowbase, seg;
    if (bid < 2048)      { src = q;  dst = qbf;  rowbase = bid * 2;          seg = -1; }
    else if (bid < 2560) { src = wq; dst = wqkv; rowbase = (bid - 2048) * 2; seg = 0; }
    else if (bid < 3072) { src = wk; dst = wqkv; rowbase = (bid - 2560) * 2; seg = 1; }
    else                 { src = wv; dst = wqkv; rowbase = (bid - 3072) * 2; seg = 2; }
    int rl = rowbase + (t >> 7);
    int k = (t & 127) * 8;
    const float* s8 = src + (size_t)rl * 1024 + k;
    f32x4 a = *(const f32x4*)s8;
    f32x4 b = *(const f32x4*)(s8 + 4);
    s16x8 r;
    r[0] = f2bf(a[0]); r[1] = f2bf(a[1]); r[2] = f2bf(a[2]); r[3] = f2bf(a[3]);
    r[4] = f2bf(b[0]); r[5] = f2bf(b[1]); r[6] = f2bf(b[2]); r[7] = f2bf(b[3]);
    int grow = (seg < 0) ? rl : (seg * 1024 + rl);
    size_t chunk = ((size_t)(grow >> 4) * 32 + (k >> 5)) * 64 +
                   ((k >> 3) & 3) * 16 + (grow & 15);
    *(s16x8*)(dst + chunk * 8) = r;
    return;
  }

  // ---- bitmask part: inline dtype detect (first 1024 words, per block) ----
  if (t == 0) { s_gt1 = 0; s_notf = 0; }
  __syncthreads();
  {
    const uint* m = (const uint*)mask;
    bool gt1 = false, notf = false;
#pragma unroll
    for (int i = 0; i < 4; ++i) {
      uint v = m[t * 4 + i];
      if (v > 1u) gt1 = true;
      if (v != 0u && v != 0x3F800000u) notf = true;
    }
    if (gt1) atomicOr(&s_gt1, 1);
    if (notf) atomicOr(&s_notf, 1);
  }
  __syncthreads();
  const int mty = s_gt1 ? (s_notf ? 0 : 2) : 1;

  int w = (bid - 3584) * 256 + t;
  int b = w >> 17;
  int rem = w & 131071;
  int qq = rem >> 6;
  int kt = rem & 63;
  uint bits = 0;
  if (mty == 0) {
    const uint* p = (const uint*)((const unsigned char*)mask +
                                  ((size_t)b * S_ + qq) * S_ + (size_t)kt * 32);
#pragma unroll
    for (int i = 0; i < 8; ++i) {
      uint v = p[i];
#pragma unroll
      for (int j = 0; j < 4; ++j)
        if ((v >> (8 * j)) & 0xffu) bits |= 1u << (i * 4 + j);
    }
  } else {
    const uint* p = (const uint*)mask + ((size_t)b * S_ + qq) * S_ + kt * 32;
#pragma unroll
    for (int i = 0; i < 32; ++i)
      if (p[i]) bits |= 1u << i;
  }
  bmT[((size_t)b * (S_ / 32) + kt) * S_ + qq] = bits;
}

// ---- fused QKV GEMM, staged: C[4096,3072] = qbf @ wqkv^T ------------------
// 1-D grid 768, XCD-grouped (3 N-panels per XCD). BK=64: two 32-k chunks per
// barrier pair (32 barrier drains instead of 64; 8 async16 in flight).
__global__ __launch_bounds__(256) void gemm_qkv_kernel(
    const short* __restrict__ A, const short* __restrict__ Bt,
    const float* __restrict__ bq, const float* __restrict__ bk,
    const float* __restrict__ bv, short* __restrict__ q_ws,
    short* __restrict__ KF, short* __restrict__ VF) {
  __shared__ short lds[16384];
  const int tid = threadIdx.x;
  const int lane = tid & 63;
  const int wave = tid >> 6;
  const int l16 = lane & 15;
  const int quad = lane >> 4;
  const int xcd = blockIdx.x & 7;
  const int slot = blockIdx.x >> 3;      // [0,96)
  const int by_ = xcd * 3 + (slot % 3);  // [0,24): N-panel, 3 per XCD
  const int bx = slot / 3;               // [0,32): M-panel
  const int mb0 = bx * 8;
  const int nb0 = by_ * 8;
  const int m0 = bx * 128 + (wave >> 1) * 64;
  const int n0 = by_ * 128 + (wave & 1) * 64;
  const int g = tid >> 6, c = tid & 63;

  f32x4 acc[4][4];
#pragma unroll
  for (int i = 0; i < 4; ++i)
#pragma unroll
    for (int j = 0; j < 4; ++j) acc[i][j] = (f32x4){0.f, 0.f, 0.f, 0.f};

  for (int kb = 0; kb < 16; ++kb) {
    // k-chunk 2kb -> region [0:8192); k-chunk 2kb+1 -> region [8192:16384)
    async16(A + (((size_t)(mb0 + g) * 32 + 2 * kb) * 64 + c) * 8, lds + tid * 8);
    async16(A + (((size_t)(mb0 + g + 4) * 32 + 2 * kb) * 64 + c) * 8,
            lds + 2048 + tid * 8);
    async16(Bt + (((size_t)(nb0 + g) * 32 + 2 * kb) * 64 + c) * 8,
            lds + 4096 + tid * 8);
    async16(Bt + (((size_t)(nb0 + g + 4) * 32 + 2 * kb) * 64 + c) * 8,
            lds + 6144 + tid * 8);
    async16(A + (((size_t)(mb0 + g) * 32 + 2 * kb + 1) * 64 + c) * 8,
            lds + 8192 + tid * 8);
    async16(A + (((size_t)(mb0 + g + 4) * 32 + 2 * kb + 1) * 64 + c) * 8,
            lds + 10240 + tid * 8);
    async16(Bt + (((size_t)(nb0 + g) * 32 + 2 * kb + 1) * 64 + c) * 8,
            lds + 12288 + tid * 8);
    async16(Bt + (((size_t)(nb0 + g + 4) * 32 + 2 * kb + 1) * 64 + c) * 8,
            lds + 14336 + tid * 8);
    __syncthreads();
#pragma unroll
    for (int h = 0; h < 2; ++h) {
      const short* base = lds + h * 8192;
      s16x8 a[4], b[4];
#pragma unroll
      for (int i = 0; i < 4; ++i)
        a[i] = *(const s16x8*)(base + (((wave >> 1) * 4 + i) * 64 + lane) * 8);
#pragma unroll
      for (int j = 0; j < 4; ++j)
        b[j] =
            *(const s16x8*)(base + 4096 + (((wave & 1) * 4 + j) * 64 + lane) * 8);
#pragma unroll
      for (int i = 0; i < 4; ++i)
#pragma unroll
        for (int j = 0; j < 4; ++j) acc[i][j] = mfma_bf16(a[i], b[j], acc[i][j]);
    }
    __syncthreads();
  }

#pragma unroll
  for (int i = 0; i < 4; ++i) {
#pragma unroll
    for (int j = 0; j < 4; ++j) {
#pragma unroll
      for (int r = 0; r < 4; ++r) {
        int m = m0 + i * 16 + quad * 4 + r;
        int n = n0 + j * 16 + l16;
        int seg = n >> 10, nl = n & 1023;
        float bias = (seg == 0) ? bq[nl] : ((seg == 1) ? bk[nl] : bv[nl]);
        float v = acc[i][j][r] + bias;
        // Q scale: 1/sqrt(DH) * log2(e), so attn can use raw exp2.
        if (seg == 0) v *= 0.18033688011112042f;
        int bb = m >> 11, s = m & (S_ - 1);
        int hh = nl >> 6, dh = nl & 63;
        int bh = bb * H_ + hh;
        short bv16 = f2bf(v);
        if (seg == 0) {
          q_ws[((size_t)bh * S_ + s) * DH_ + dh] = bv16;
        } else if (seg == 1) {
          int kt = s >> 5, r5 = s & 31;
          int kkb = r5 >> 4, kl16 = r5 & 15;
          int kf = dh >> 5, qd = (dh >> 3) & 3, e = dh & 7;
          KF[(size_t)bh * 131072 +
             ((size_t)kt * 256 + (kkb * 2 + kf) * 64 + qd * 16 + kl16) * 8 + e] = bv16;
        } else {
          int kt = s >> 5, ko = s & 31;
          int hi = ko >> 4, qd = (ko >> 2) & 3, j4 = ko & 3;
          int nb = dh >> 4, vl16 = dh & 15, e = hi * 4 + j4;
          VF[(size_t)bh * 131072 +
             ((size_t)kt * 256 + nb * 64 + qd * 16 + vl16) * 8 + e] = bv16;
        }
      }
    }
  }
}

// ---- attention: 512 blocks x 8 waves; wave = 32 q-rows x 32-key half ------
// EXACT R15 body (53.2us twice-measured). Barrier-free; direct-L2 K/V
// (XCD-grouped, bid&7 -> bh group). LDS only for final reduction.
__global__ __launch_bounds__(512, 4) void attn_kernel(
    const short* __restrict__ Q, const short* __restrict__ KF,
    const short* __restrict__ VF, const uint* __restrict__ bmT,
    short* __restrict__ ctx_out) {
  __shared__ float fl[8704];             // cross-wave reduce scratch (34.8 KB)
  const int tid = threadIdx.x;           // [0,512)
  const int lane = tid & 63;
  const int wave = tid >> 6;             // [0,8)
  const int qw = wave >> 1;              // [0,4): which 32-q subtile
  const int kbt = wave & 1;              // which 32-key half this wave owns
  const int l16 = lane & 15;
  const int quad = lane >> 4;
  const int xcd = blockIdx.x & 7;        // hw XCD round-robin digit
  const int slot = blockIdx.x >> 3;      // [0,64)
  const int bh = xcd * 4 + (slot >> 4);  // 32 bh, grouped 4-per-XCD
  const int qt128 = slot & 15;
  const int b = bh >> 4;
  const int h = bh & 15;
  const int qbase = qt128 * 128 + qw * 32;

  const short* Qh = Q + (size_t)bh * S_ * DH_;
  // per-wave half-tile fragment bases (same offsets the LDS path used)
  const short* Kh = KF + (size_t)bh * 131072 + kbt * 2048 + lane * 8;
  const short* Vh = VF + (size_t)bh * 131072 + kbt * 2048 + lane * 8;
  const uint* bmb = bmT + (size_t)b * (S_ / 32) * S_;

  s16x8 qf[2][2];
#pragma unroll
  for (int qg = 0; qg < 2; ++qg)
#pragma unroll
    for (int kf = 0; kf < 2; ++kf)
      qf[qg][kf] = *(const s16x8*)(Qh + (size_t)(qbase + qg * 16 + l16) * DH_ +
                                   kf * 32 + quad * 8);

  f32x4 ctx[2][4];
#pragma unroll
  for (int qg = 0; qg < 2; ++qg)
#pragma unroll
    for (int nb = 0; nb < 4; ++nb) ctx[qg][nb] = (f32x4){0.f, 0.f, 0.f, 0.f};
  float ls[2] = {0.f, 0.f};

  // mask words: wc = tile t, wn = tile t+1; prefetch t+2 inside the body.
  uint wc0 = bmb[(size_t)kbt * S_ + qbase + l16];
  uint wc1 = bmb[(size_t)kbt * S_ + qbase + 16 + l16];
  uint wn0 = bmb[(size_t)(2 + kbt) * S_ + qbase + l16];
  uint wn1 = bmb[(size_t)(2 + kbt) * S_ + qbase + 16 + l16];

  // K register double-buffer (static A/B sets; no runtime indexing)
  s16x8 kaA[2][2], kaB[2][2];
#pragma unroll
  for (int kb = 0; kb < 2; ++kb)
#pragma unroll
    for (int kf = 0; kf < 2; ++kf)
      kaA[kb][kf] = *(const s16x8*)(Kh + (kb * 2 + kf) * 512);

  // body for tile T: K for T already in KC; prefetch K(T+1) into KN (if PREF),
  // masks for T+2; V(T) loaded here, consumed after softmax.
#define ATTN_TILE(KC, KN, T, PREF)                                            \
  {                                                                           \
    if (PREF) {                                                               \
      const short* kp = Kh + (size_t)((T) + 1) * 4096;                        \
      _Pragma("unroll") for (int kb = 0; kb < 2; ++kb)                        \
          _Pragma("unroll") for (int kf = 0; kf < 2; ++kf)                    \
              KN[kb][kf] = *(const s16x8*)(kp + (kb * 2 + kf) * 512);         \
    }                                                                         \
    uint a0 = 0, a1 = 0;                                                      \
    if ((T) + 2 < 32) {                                                       \
      a0 = bmb[(size_t)(2 * (T) + 4 + kbt) * S_ + qbase + l16];               \
      a1 = bmb[(size_t)(2 * (T) + 4 + kbt) * S_ + qbase + 16 + l16];          \
    }                                                                         \
    const short* vp = Vh + (size_t)(T) * 4096;                                \
    s16x8 vb[4];                                                              \
    _Pragma("unroll") for (int nb = 0; nb < 4; ++nb)                          \
        vb[nb] = *(const s16x8*)(vp + nb * 512);                              \
    s16x8 pa[2];                                                              \
    const uint wsh0 = wc0 >> (quad * 4);                                      \
    const uint wsh1 = wc1 >> (quad * 4);                                      \
    _Pragma("unroll") for (int qg = 0; qg < 2; ++qg) {                        \
      f32x4 sc[2];                                                            \
      _Pragma("unroll") for (int kb = 0; kb < 2; ++kb) {                      \
        f32x4 t0 =                                                            \
            mfma_bf16(KC[kb][0], qf[qg][0], (f32x4){0.f, 0.f, 0.f, 0.f});     \
        sc[kb] = mfma_bf16(KC[kb][1], qf[qg][1], t0);                         \
      }                                                                       \
      const uint wsh = qg ? wsh1 : wsh0;                                      \
      float sum = 0.f;                                                        \
      _Pragma("unroll") for (int kb = 0; kb < 2; ++kb)                        \
          _Pragma("unroll") for (int r = 0; r < 4; ++r) {                     \
        int bit = (wsh >> (kb * 16 + r)) & 1;                                 \
        float p = bit ? 0.f : __builtin_amdgcn_exp2f(sc[kb][r]);              \
        sum += p;                                                             \
        pa[qg][kb * 4 + r] = f2bf_rn(p);                                      \
      }                                                                       \
      ls[qg] += sum;                                                          \
    }                                                                         \
    _Pragma("unroll") for (int nb = 0; nb < 4; ++nb)                          \
        _Pragma("unroll") for (int qg = 0; qg < 2; ++qg)                      \
            ctx[qg][nb] = mfma_bf16(pa[qg], vb[nb], ctx[qg][nb]);             \
    wc0 = wn0;                                                                \
    wc1 = wn1;                                                                \
    wn0 = a0;                                                                 \
    wn1 = a1;                                                                 \
  }

  for (int t2 = 0; t2 < 16; ++t2) {
    ATTN_TILE(kaA, kaB, 2 * t2, 1)
    ATTN_TILE(kaB, kaA, 2 * t2 + 1, (t2 < 15))
  }
#undef ATTN_TILE

  // ---- cross-wave key-half reduction (elementwise, same lane) ----
  const int foff = qw * 2176;  // 2048 ctx + 128 ls floats per qw
  if (kbt) {
#pragma unroll
    for (int qg = 0; qg < 2; ++qg) {
#pragma unroll
      for (int nb = 0; nb < 4; ++nb)
#pragma unroll
        for (int r = 0; r < 4; ++r)
          fl[foff + ((qg * 4 + nb) * 4 + r) * 64 + lane] = ctx[qg][nb][r];
      fl[foff + 2048 + qg * 64 + lane] = ls[qg];
    }
  }
  __syncthreads();
  if (!kbt) {
#pragma unroll
    for (int qg = 0; qg < 2; ++qg) {
#pragma unroll
      for (int nb = 0; nb < 4; ++nb)
#pragma unroll
        for (int r = 0; r < 4; ++r)
          ctx[qg][nb][r] += fl[foff + ((qg * 4 + nb) * 4 + r) * 64 + lane];
      ls[qg] += fl[foff + 2048 + qg * 64 + lane];
      ls[qg] += __shfl_xor(ls[qg], 16);
      ls[qg] += __shfl_xor(ls[qg], 32);
    }

    // epilogue: ctx C-layout row = q(quad*4+r), col = dh(l16)
#pragma unroll
    for (int qg = 0; qg < 2; ++qg)
#pragma unroll
      for (int r = 0; r < 4; ++r) {
        float lr = __shfl(ls[qg], quad * 4 + r);
        float inv = 1.f / lr;
        int srow = qbase + qg * 16 + quad * 4 + r;
#pragma unroll
        for (int nb = 0; nb < 4; ++nb) {
          int col = h * DH_ + nb * 16 + l16;
          ctx_out[(size_t)(b * S_ + srow) * D_ + col] = f2bf(ctx[qg][nb][r] * inv);
        }
      }
  }
}

// ---- final GEMM: out[4096,1024] fp32 = ctx_bf16 @ Wo^T + bo ---------------
// 1-D grid 256, XCD-grouped. Wo read as fp32 and converted to bf16 during
// B-staging (ds_write_b128) -- convert_wo kernel eliminated.
__global__ __launch_bounds__(256) void gemm_final_kernel(
    const short* __restrict__ A, const float* __restrict__ Wo,
    const float* __restrict__ bias, float* __restrict__ out) {
  __shared__ short lds[8192];
  const int tid = threadIdx.x;
  const int lane = tid & 63;
  const int wave = tid >> 6;
  const int l16 = lane & 15;
  const int quad = lane >> 4;
  const int m0 = (blockIdx.x >> 3) * 128;
  const int n0 = (blockIdx.x & 7) * 128;
  const int g = tid >> 6, c = tid & 63;
  const int r15 = c & 15, qd = c >> 4;

  f32x4 acc[4][4];
#pragma unroll
  for (int i = 0; i < 4; ++i)
#pragma unroll
    for (int j = 0; j < 4; ++j) acc[i][j] = (f32x4){0.f, 0.f, 0.f, 0.f};

  for (int k0 = 0; k0 < 1024; k0 += 32) {
    async16(A + (size_t)(m0 + g * 16 + r15) * 1024 + k0 + qd * 8, lds + tid * 8);
    async16(A + (size_t)(m0 + (g + 4) * 16 + r15) * 1024 + k0 + qd * 8,
            lds + 2048 + tid * 8);
    // B: Wo fp32 -> bf16 -> LDS (same entries the async16 path produced)
    {
      const float* w0p = Wo + (size_t)(n0 + g * 16 + r15) * 1024 + k0 + qd * 8;
      f32x4 x = *(const f32x4*)w0p;
      f32x4 y = *(const f32x4*)(w0p + 4);
      s16x8 r0;
      r0[0] = f2bf_rn(x[0]); r0[1] = f2bf_rn(x[1]);
      r0[2] = f2bf_rn(x[2]); r0[3] = f2bf_rn(x[3]);
      r0[4] = f2bf_rn(y[0]); r0[5] = f2bf_rn(y[1]);
      r0[6] = f2bf_rn(y[2]); r0[7] = f2bf_rn(y[3]);
      *(s16x8*)(lds + 4096 + tid * 8) = r0;
      const float* w1p =
          Wo + (size_t)(n0 + (g + 4) * 16 + r15) * 1024 + k0 + qd * 8;
      f32x4 u = *(const f32x4*)w1p;
      f32x4 v = *(const f32x4*)(w1p + 4);
      s16x8 r1;
      r1[0] = f2bf_rn(u[0]); r1[1] = f2bf_rn(u[1]);
      r1[2] = f2bf_rn(u[2]); r1[3] = f2bf_rn(u[3]);
      r1[4] = f2bf_rn(v[0]); r1[5] = f2bf_rn(v[1]);
      r1[6] = f2bf_rn(v[2]); r1[7] = f2bf_rn(v[3]);
      *(s16x8*)(lds + 6144 + tid * 8) = r1;
    }
    __syncthreads();
    s16x8 a[4], b[4];
#pragma unroll
    for (int i = 0; i < 4; ++i)
      a[i] = *(const s16x8*)(lds + (((wave >> 1) * 4 + i) * 64 + lane) * 8);
#pragma unroll
    for (int j = 0; j < 4; ++j)
      b[j] = *(const s16x8*)(lds + 4096 + (((wave & 1) * 4 + j) * 64 + lane) * 8);
#pragma unroll
    for (int i = 0; i < 4; ++i)
#pragma unroll
      for (int j = 0; j < 4; ++j) acc[i][j] = mfma_bf16(a[i], b[j], acc[i][j]);
    __syncthreads();
  }

  const int mw = m0 + (wave >> 1) * 64;
  const int nw = n0 + (wave & 1) * 64;
#pragma unroll
  for (int i = 0; i < 4; ++i)
#pragma unroll
    for (int j = 0; j < 4; ++j)
#pragma unroll
      for (int r = 0; r < 4; ++r) {
        int m = mw + i * 16 + quad * 4 + r;
        int n = nw + j * 16 + l16;
        out[(size_t)m * 1024 + n] = acc[i][j][r] + bias[n];
      }
}

extern "C" void kernel_launch(void* const* d_in, const int* in_sizes, int n_in,
                              void* d_out, int out_size, void* d_ws,
                              size_t ws_size, hipStream_t stream) {
  const float* query = (const float*)d_in[0];
  const void* mask = d_in[1];
  const float* Wq = (const float*)d_in[2];
  const float* bq = (const float*)d_in[3];
  const float* Wk = (const float*)d_in[4];
  const float* bk = (const float*)d_in[5];
  const float* Wv = (const float*)d_in[6];
  const float* bv = (const float*)d_in[7];
  const float* Wo = (const float*)d_in[8];
  const float* bo = (const float*)d_in[9];

  const size_t NE = (size_t)B_ * S_ * D_;  // 4194304
  short* ws_s = (short*)d_ws;
  short* q_ws = ws_s;             // [B,H,S,DH] bf16 row-major (8 MB)
  short* KF = ws_s + NE;          // K fragment-order (8 MB)
  short* VF = ws_s + 2 * NE;      // V fragment-order, PV-permuted (8 MB)
  short* ctx_ws = ws_s + 3 * NE;  // [B,S,D] bf16 row-major (8 MB)
  // scratch inside d_out (all dead before the final GEMM runs):
  short* qbf = (short*)d_out;          // [0:8M)  query bf16, fragment order
  short* wqkv = qbf + NE;              // [8:14M) Wq|Wk|Wv bf16, fragment order
  uint* bmT = (uint*)(wqkv + 3145728); // [14:15M) bitmask

  prep_kernel<<<4608, 256, 0, stream>>>(query, Wq, Wk, Wv, mask, qbf, wqkv,
                                        bmT);

  gemm_qkv_kernel<<<768, 256, 0, stream>>>(qbf, wqkv, bq, bk, bv, q_ws, KF,
                                           VF);

  attn_kernel<<<512, 512, 0, stream>>>(q_ws, KF, VF, bmT, ctx_ws);

  gemm_final_kernel<<<256, 256, 0, stream>>>(ctx_ws, Wo, bo, (float*)d_out);
}

// Round 12
// 234.856 us; speedup vs baseline: 1.1653x; 1.1653x over previous
//
#include <hip/hip_runtime.h>

// MultiHeadedAttention: B=2, S=2048, D=1024, H=16, DH=64. fp32 in/out.
// R21: R20 post-mortem -- BK=64 qkv regressed (57.2us, VGPR 88, occ 14%);
// revert qkv to round-6 dim3(32,24) BK=32 (proven). Revert Wo-fold
// (convert_wo restored). attn stays byte-exact R15 (53.2us).
// NEW: gemm_final retiled 128x128 -> 64x128 (512 blocks = 2 blocks/CU =
// 2 waves/SIMD instead of 1): a co-resident block now covers each barrier
// drain. bid&7 keeps one 256KB Wo panel per XCD. acc[4][2], LDS 12KB.
// Merged prep kept (3x correctness-proven, saves 2 launches).
#define B_ 2
#define S_ 2048
#define D_ 1024
#define H_ 16
#define DH_ 64

typedef float f32x4 __attribute__((ext_vector_type(4)));
typedef short s16x8 __attribute__((ext_vector_type(8)));
typedef __bf16 bf16x8 __attribute__((ext_vector_type(8)));
typedef unsigned int uint;

// ---- MFMA wrapper: tolerate either builtin signature (short8 or bf16x8) ----
template <typename T>
static __device__ auto mfma_sel(T a, T b, f32x4 c, int)
    -> decltype(__builtin_amdgcn_mfma_f32_16x16x32_bf16(a, b, c, 0, 0, 0)) {
  return __builtin_amdgcn_mfma_f32_16x16x32_bf16(a, b, c, 0, 0, 0);
}
template <typename T>
static __device__ f32x4 mfma_sel(T a, T b, f32x4 c, long) {
  return __builtin_amdgcn_mfma_f32_16x16x32_bf16(
      __builtin_bit_cast(bf16x8, a), __builtin_bit_cast(bf16x8, b), c, 0, 0, 0);
}
static __device__ __forceinline__ f32x4 mfma_bf16(s16x8 a, s16x8 b, f32x4 c) {
  return mfma_sel(a, b, c, 0);
}

static __device__ __forceinline__ short f2bf(float f) {
  unsigned u = __float_as_uint(f);
  u += 0x7fffu + ((u >> 16) & 1u);
  return (short)(u >> 16);
}

// hardware RNE convert (v_cvt_pk_bf16_f32) -- bit-identical to f2bf for
// non-NaN inputs.
static __device__ __forceinline__ short f2bf_rn(float f) {
  return __builtin_bit_cast(short, (__bf16)f);
}

// ---- async 16B global -> LDS (per-lane GLOBAL addr ok; LDS side = base+lane*16)
static __device__ __forceinline__ void async16(const short* g, short* l) {
  __builtin_amdgcn_global_load_lds(
      (const __attribute__((address_space(1))) unsigned int*)g,
      (__attribute__((address_space(3))) unsigned int*)l, 16, 0, 0);
}

// ---- merged prep: blocks [0,3584) fp32->bf16 fragment convert;
//      blocks [3584,4608) mask->bitmask with per-block inline dtype detect --
__global__ __launch_bounds__(256) void prep_kernel(
    const float* __restrict__ q, const float* __restrict__ wq,
    const float* __restrict__ wk, const float* __restrict__ wv,
    const void* __restrict__ mask, short* __restrict__ qbf,
    short* __restrict__ wqkv, uint* __restrict__ bmT) {
  __shared__ int s_gt1, s_notf;
  const int bid = blockIdx.x;
  const int t = threadIdx.x;

  if (bid < 3584) {
    // ---- convert part (unchanged math) ----
    const float* src;
    short* dst;
    int rowbase, seg;
    if (bid < 2048)      { src = q;  dst = qbf;  rowbase = bid * 2;          seg = -1; }
    else if (bid < 2560) { src = wq; dst = wqkv; rowbase = (bid - 2048) * 2; seg = 0; }
    else if (bid < 3072) { src = wk; dst = wqkv; rowbase = (bid - 2560) * 2; seg = 1; }
    else                 { src = wv; dst = wqkv; rowbase = (bid - 3072) * 2; seg = 2; }
    int rl = rowbase + (t >> 7);
    int k = (t & 127) * 8;
    const float* s8 = src + (size_t)rl * 1024 + k;
    f32x4 a = *(const f32x4*)s8;
    f32x4 b = *(const f32x4*)(s8 + 4);
    s16x8 r;
    r[0] = f2bf(a[0]); r[1] = f2bf(a[1]); r[2] = f2bf(a[2]); r[3] = f2bf(a[3]);
    r[4] = f2bf(b[0]); r[5] = f2bf(b[1]); r[6] = f2bf(b[2]); r[7] = f2bf(b[3]);
    int grow = (seg < 0) ? rl : (seg * 1024 + rl);
    size_t chunk = ((size_t)(grow >> 4) * 32 + (k >> 5)) * 64 +
                   ((k >> 3) & 3) * 16 + (grow & 15);
    *(s16x8*)(dst + chunk * 8) = r;
    return;
  }

  // ---- bitmask part: inline dtype detect (first 1024 words, per block) ----
  if (t == 0) { s_gt1 = 0; s_notf = 0; }
  __syncthreads();
  {
    const uint* m = (const uint*)mask;
    bool gt1 = false, notf = false;
#pragma unroll
    for (int i = 0; i < 4; ++i) {
      uint v = m[t * 4 + i];
      if (v > 1u) gt1 = true;
      if (v != 0u && v != 0x3F800000u) notf = true;
    }
    if (gt1) atomicOr(&s_gt1, 1);
    if (notf) atomicOr(&s_notf, 1);
  }
  __syncthreads();
  const int mty = s_gt1 ? (s_notf ? 0 : 2) : 1;

  int w = (bid - 3584) * 256 + t;
  int b = w >> 17;
  int rem = w & 131071;
  int qq = rem >> 6;
  int kt = rem & 63;
  uint bits = 0;
  if (mty == 0) {
    const uint* p = (const uint*)((const unsigned char*)mask +
                                  ((size_t)b * S_ + qq) * S_ + (size_t)kt * 32);
#pragma unroll
    for (int i = 0; i < 8; ++i) {
      uint v = p[i];
#pragma unroll
      for (int j = 0; j < 4; ++j)
        if ((v >> (8 * j)) & 0xffu) bits |= 1u << (i * 4 + j);
    }
  } else {
    const uint* p = (const uint*)mask + ((size_t)b * S_ + qq) * S_ + kt * 32;
#pragma unroll
    for (int i = 0; i < 32; ++i)
      if (p[i]) bits |= 1u << i;
  }
  bmT[((size_t)b * (S_ / 32) + kt) * S_ + qq] = bits;
}

// ---- fp32 -> bf16 row-major convert for Wo (runs AFTER attn, into q_ws) ----
__global__ __launch_bounds__(256) void convert_wo_kernel(
    const float* __restrict__ wo, short* __restrict__ wob) {
  size_t i = ((size_t)blockIdx.x * 256 + threadIdx.x) * 8;
  f32x4 a = *(const f32x4*)(wo + i);
  f32x4 b = *(const f32x4*)(wo + i + 4);
  s16x8 r;
  r[0] = f2bf(a[0]); r[1] = f2bf(a[1]); r[2] = f2bf(a[2]); r[3] = f2bf(a[3]);
  r[4] = f2bf(b[0]); r[5] = f2bf(b[1]); r[6] = f2bf(b[2]); r[7] = f2bf(b[3]);
  *(s16x8*)(wob + i) = r;
}

// ---- fused QKV GEMM, staged: C[4096,3072] = qbf @ wqkv^T (round-6 form) ---
__global__ __launch_bounds__(256) void gemm_qkv_kernel(
    const short* __restrict__ A, const short* __restrict__ Bt,
    const float* __restrict__ bq, const float* __restrict__ bk,
    const float* __restrict__ bv, short* __restrict__ q_ws,
    short* __restrict__ KF, short* __restrict__ VF) {
  __shared__ short lds[8192];
  const int tid = threadIdx.x;
  const int lane = tid & 63;
  const int wave = tid >> 6;
  const int l16 = lane & 15;
  const int quad = lane >> 4;
  const int mb0 = blockIdx.x * 8;
  const int nb0 = blockIdx.y * 8;
  const int m0 = blockIdx.x * 128 + (wave >> 1) * 64;
  const int n0 = blockIdx.y * 128 + (wave & 1) * 64;
  const int g = tid >> 6, c = tid & 63;

  f32x4 acc[4][4];
#pragma unroll
  for (int i = 0; i < 4; ++i)
#pragma unroll
    for (int j = 0; j < 4; ++j) acc[i][j] = (f32x4){0.f, 0.f, 0.f, 0.f};

  for (int kb = 0; kb < 32; ++kb) {
    async16(A + (((size_t)(mb0 + g) * 32 + kb) * 64 + c) * 8, lds + tid * 8);
    async16(A + (((size_t)(mb0 + g + 4) * 32 + kb) * 64 + c) * 8,
            lds + 2048 + tid * 8);
    async16(Bt + (((size_t)(nb0 + g) * 32 + kb) * 64 + c) * 8,
            lds + 4096 + tid * 8);
    async16(Bt + (((size_t)(nb0 + g + 4) * 32 + kb) * 64 + c) * 8,
            lds + 6144 + tid * 8);
    __syncthreads();
    s16x8 a[4], b[4];
#pragma unroll
    for (int i = 0; i < 4; ++i)
      a[i] = *(const s16x8*)(lds + (((wave >> 1) * 4 + i) * 64 + lane) * 8);
#pragma unroll
    for (int j = 0; j < 4; ++j)
      b[j] = *(const s16x8*)(lds + 4096 + (((wave & 1) * 4 + j) * 64 + lane) * 8);
#pragma unroll
    for (int i = 0; i < 4; ++i)
#pragma unroll
      for (int j = 0; j < 4; ++j) acc[i][j] = mfma_bf16(a[i], b[j], acc[i][j]);
    __syncthreads();
  }

#pragma unroll
  for (int i = 0; i < 4; ++i) {
#pragma unroll
    for (int j = 0; j < 4; ++j) {
#pragma unroll
      for (int r = 0; r < 4; ++r) {
        int m = m0 + i * 16 + quad * 4 + r;
        int n = n0 + j * 16 + l16;
        int seg = n >> 10, nl = n & 1023;
        float bias = (seg == 0) ? bq[nl] : ((seg == 1) ? bk[nl] : bv[nl]);
        float v = acc[i][j][r] + bias;
        // Q scale: 1/sqrt(DH) * log2(e), so attn can use raw exp2.
        if (seg == 0) v *= 0.18033688011112042f;
        int bb = m >> 11, s = m & (S_ - 1);
        int hh = nl >> 6, dh = nl & 63;
        int bh = bb * H_ + hh;
        short bv16 = f2bf(v);
        if (seg == 0) {
          q_ws[((size_t)bh * S_ + s) * DH_ + dh] = bv16;
        } else if (seg == 1) {
          int kt = s >> 5, r5 = s & 31;
          int kkb = r5 >> 4, kl16 = r5 & 15;
          int kf = dh >> 5, qd = (dh >> 3) & 3, e = dh & 7;
          KF[(size_t)bh * 131072 +
             ((size_t)kt * 256 + (kkb * 2 + kf) * 64 + qd * 16 + kl16) * 8 + e] = bv16;
        } else {
          int kt = s >> 5, ko = s & 31;
          int hi = ko >> 4, qd = (ko >> 2) & 3, j4 = ko & 3;
          int nb = dh >> 4, vl16 = dh & 15, e = hi * 4 + j4;
          VF[(size_t)bh * 131072 +
             ((size_t)kt * 256 + nb * 64 + qd * 16 + vl16) * 8 + e] = bv16;
        }
      }
    }
  }
}

// ---- attention: 512 blocks x 8 waves; wave = 32 q-rows x 32-key half ------
// EXACT R15 body (53.2us twice-measured). Barrier-free; direct-L2 K/V
// (XCD-grouped, bid&7 -> bh group). LDS only for final reduction.
__global__ __launch_bounds__(512, 4) void attn_kernel(
    const short* __restrict__ Q, const short* __restrict__ KF,
    const short* __restrict__ VF, const uint* __restrict__ bmT,
    short* __restrict__ ctx_out) {
  __shared__ float fl[8704];             // cross-wave reduce scratch (34.8 KB)
  const int tid = threadIdx.x;           // [0,512)
  const int lane = tid & 63;
  const int wave = tid >> 6;             // [0,8)
  const int qw = wave >> 1;              // [0,4): which 32-q subtile
  const int kbt = wave & 1;              // which 32-key half this wave owns
  const int l16 = lane & 15;
  const int quad = lane >> 4;
  const int xcd = blockIdx.x & 7;        // hw XCD round-robin digit
  const int slot = blockIdx.x >> 3;      // [0,64)
  const int bh = xcd * 4 + (slot >> 4);  // 32 bh, grouped 4-per-XCD
  const int qt128 = slot & 15;
  const int b = bh >> 4;
  const int h = bh & 15;
  const int qbase = qt128 * 128 + qw * 32;

  const short* Qh = Q + (size_t)bh * S_ * DH_;
  // per-wave half-tile fragment bases (same offsets the LDS path used)
  const short* Kh = KF + (size_t)bh * 131072 + kbt * 2048 + lane * 8;
  const short* Vh = VF + (size_t)bh * 131072 + kbt * 2048 + lane * 8;
  const uint* bmb = bmT + (size_t)b * (S_ / 32) * S_;

  s16x8 qf[2][2];
#pragma unroll
  for (int qg = 0; qg < 2; ++qg)
#pragma unroll
    for (int kf = 0; kf < 2; ++kf)
      qf[qg][kf] = *(const s16x8*)(Qh + (size_t)(qbase + qg * 16 + l16) * DH_ +
                                   kf * 32 + quad * 8);

  f32x4 ctx[2][4];
#pragma unroll
  for (int qg = 0; qg < 2; ++qg)
#pragma unroll
    for (int nb = 0; nb < 4; ++nb) ctx[qg][nb] = (f32x4){0.f, 0.f, 0.f, 0.f};
  float ls[2] = {0.f, 0.f};

  // mask words: wc = tile t, wn = tile t+1; prefetch t+2 inside the body.
  uint wc0 = bmb[(size_t)kbt * S_ + qbase + l16];
  uint wc1 = bmb[(size_t)kbt * S_ + qbase + 16 + l16];
  uint wn0 = bmb[(size_t)(2 + kbt) * S_ + qbase + l16];
  uint wn1 = bmb[(size_t)(2 + kbt) * S_ + qbase + 16 + l16];

  // K register double-buffer (static A/B sets; no runtime indexing)
  s16x8 kaA[2][2], kaB[2][2];
#pragma unroll
  for (int kb = 0; kb < 2; ++kb)
#pragma unroll
    for (int kf = 0; kf < 2; ++kf)
      kaA[kb][kf] = *(const s16x8*)(Kh + (kb * 2 + kf) * 512);

  // body for tile T: K for T already in KC; prefetch K(T+1) into KN (if PREF),
  // masks for T+2; V(T) loaded here, consumed after softmax.
#define ATTN_TILE(KC, KN, T, PREF)                                            \
  {                                                                           \
    if (PREF) {                                                               \
      const short* kp = Kh + (size_t)((T) + 1) * 4096;                        \
      _Pragma("unroll") for (int kb = 0; kb < 2; ++kb)                        \
          _Pragma("unroll") for (int kf = 0; kf < 2; ++kf)                    \
              KN[kb][kf] = *(const s16x8*)(kp + (kb * 2 + kf) * 512);         \
    }                                                                         \
    uint a0 = 0, a1 = 0;                                                      \
    if ((T) + 2 < 32) {                                                       \
      a0 = bmb[(size_t)(2 * (T) + 4 + kbt) * S_ + qbase + l16];               \
      a1 = bmb[(size_t)(2 * (T) + 4 + kbt) * S_ + qbase + 16 + l16];          \
    }                                                                         \
    const short* vp = Vh + (size_t)(T) * 4096;                                \
    s16x8 vb[4];                                                              \
    _Pragma("unroll") for (int nb = 0; nb < 4; ++nb)                          \
        vb[nb] = *(const s16x8*)(vp + nb * 512);                              \
    s16x8 pa[2];                                                              \
    const uint wsh0 = wc0 >> (quad * 4);                                      \
    const uint wsh1 = wc1 >> (quad * 4);                                      \
    _Pragma("unroll") for (int qg = 0; qg < 2; ++qg) {                        \
      f32x4 sc[2];                                                            \
      _Pragma("unroll") for (int kb = 0; kb < 2; ++kb) {                      \
        f32x4 t0 =                                                            \
            mfma_bf16(KC[kb][0], qf[qg][0], (f32x4){0.f, 0.f, 0.f, 0.f});     \
        sc[kb] = mfma_bf16(KC[kb][1], qf[qg][1], t0);                         \
      }                                                                       \
      const uint wsh = qg ? wsh1 : wsh0;                                      \
      float sum = 0.f;                                                        \
      _Pragma("unroll") for (int kb = 0; kb < 2; ++kb)                        \
          _Pragma("unroll") for (int r = 0; r < 4; ++r) {                     \
        int bit = (wsh >> (kb * 16 + r)) & 1;                                 \
        float p = bit ? 0.f : __builtin_amdgcn_exp2f(sc[kb][r]);              \
        sum += p;                                                             \
        pa[qg][kb * 4 + r] = f2bf_rn(p);                                      \
      }                                                                       \
      ls[qg] += sum;                                                          \
    }                                                                         \
    _Pragma("unroll") for (int nb = 0; nb < 4; ++nb)                          \
        _Pragma("unroll") for (int qg = 0; qg < 2; ++qg)                      \
            ctx[qg][nb] = mfma_bf16(pa[qg], vb[nb], ctx[qg][nb]);             \
    wc0 = wn0;                                                                \
    wc1 = wn1;                                                                \
    wn0 = a0;                                                                 \
    wn1 = a1;                                                                 \
  }

  for (int t2 = 0; t2 < 16; ++t2) {
    ATTN_TILE(kaA, kaB, 2 * t2, 1)
    ATTN_TILE(kaB, kaA, 2 * t2 + 1, (t2 < 15))
  }
#undef ATTN_TILE

  // ---- cross-wave key-half reduction (elementwise, same lane) ----
  const int foff = qw * 2176;  // 2048 ctx + 128 ls floats per qw
  if (kbt) {
#pragma unroll
    for (int qg = 0; qg < 2; ++qg) {
#pragma unroll
      for (int nb = 0; nb < 4; ++nb)
#pragma unroll
        for (int r = 0; r < 4; ++r)
          fl[foff + ((qg * 4 + nb) * 4 + r) * 64 + lane] = ctx[qg][nb][r];
      fl[foff + 2048 + qg * 64 + lane] = ls[qg];
    }
  }
  __syncthreads();
  if (!kbt) {
#pragma unroll
    for (int qg = 0; qg < 2; ++qg) {
#pragma unroll
      for (int nb = 0; nb < 4; ++nb)
#pragma unroll
        for (int r = 0; r < 4; ++r)
          ctx[qg][nb][r] += fl[foff + ((qg * 4 + nb) * 4 + r) * 64 + lane];
      ls[qg] += fl[foff + 2048 + qg * 64 + lane];
      ls[qg] += __shfl_xor(ls[qg], 16);
      ls[qg] += __shfl_xor(ls[qg], 32);
    }

    // epilogue: ctx C-layout row = q(quad*4+r), col = dh(l16)
#pragma unroll
    for (int qg = 0; qg < 2; ++qg)
#pragma unroll
      for (int r = 0; r < 4; ++r) {
        float lr = __shfl(ls[qg], quad * 4 + r);
        float inv = 1.f / lr;
        int srow = qbase + qg * 16 + quad * 4 + r;
#pragma unroll
        for (int nb = 0; nb < 4; ++nb) {
          int col = h * DH_ + nb * 16 + l16;
          ctx_out[(size_t)(b * S_ + srow) * D_ + col] = f2bf(ctx[qg][nb][r] * inv);
        }
      }
  }
}

// ---- final GEMM: out[4096,1024] fp32 = ctx_bf16 @ Wo_bf16^T + bo ----------
// 64x128 tile, 512 blocks (2 blocks/CU, 2 waves/SIMD). bid&7 = Wo panel
// (one 256KB panel per XCD). Wave w owns n-cols [w*32, w*32+32); acc[4][2].
__global__ __launch_bounds__(256) void gemm_final_kernel(
    const short* __restrict__ A, const short* __restrict__ Bt,
    const float* __restrict__ bias, float* __restrict__ out) {
  __shared__ short lds[6144];  // A 64x32 [0:2048) | B 128x32 [2048:6144)
  const int tid = threadIdx.x;
  const int lane = tid & 63;
  const int wave = tid >> 6;   // [0,4): n-quadrant of the 128-col tile
  const int l16 = lane & 15;
  const int quad = lane >> 4;
  const int m0 = (blockIdx.x >> 3) * 64;
  const int n0 = (blockIdx.x & 7) * 128;
  const int g = tid >> 6, c = tid & 63;
  const int r15 = c & 15, qd = c >> 4;

  f32x4 acc[4][2];
#pragma unroll
  for (int i = 0; i < 4; ++i)
#pragma unroll
    for (int j = 0; j < 2; ++j) acc[i][j] = (f32x4){0.f, 0.f, 0.f, 0.f};

  for (int k0 = 0; k0 < 1024; k0 += 32) {
    async16(A + (size_t)(m0 + g * 16 + r15) * 1024 + k0 + qd * 8, lds + tid * 8);
    async16(Bt + (size_t)(n0 + g * 16 + r15) * 1024 + k0 + qd * 8,
            lds + 2048 + tid * 8);
    async16(Bt + (size_t)(n0 + (g + 4) * 16 + r15) * 1024 + k0 + qd * 8,
            lds + 4096 + tid * 8);
    __syncthreads();
    s16x8 a[4], b[2];
#pragma unroll
    for (int i = 0; i < 4; ++i)
      a[i] = *(const s16x8*)(lds + ((i * 64 + lane) * 8));
#pragma unroll
    for (int j = 0; j < 2; ++j)
      b[j] = *(const s16x8*)(lds + 2048 + (((wave * 2 + j) * 64 + lane) * 8));
#pragma unroll
    for (int i = 0; i < 4; ++i)
#pragma unroll
      for (int j = 0; j < 2; ++j) acc[i][j] = mfma_bf16(a[i], b[j], acc[i][j]);
    __syncthreads();
  }

#pragma unroll
  for (int i = 0; i < 4; ++i)
#pragma unroll
    for (int j = 0; j < 2; ++j)
#pragma unroll
      for (int r = 0; r < 4; ++r) {
        int m = m0 + i * 16 + quad * 4 + r;
        int n = n0 + wave * 32 + j * 16 + l16;
        out[(size_t)m * 1024 + n] = acc[i][j][r] + bias[n];
      }
}

extern "C" void kernel_launch(void* const* d_in, const int* in_sizes, int n_in,
                              void* d_out, int out_size, void* d_ws,
                              size_t ws_size, hipStream_t stream) {
  const float* query = (const float*)d_in[0];
  const void* mask = d_in[1];
  const float* Wq = (const float*)d_in[2];
  const float* bq = (const float*)d_in[3];
  const float* Wk = (const float*)d_in[4];
  const float* bk = (const float*)d_in[5];
  const float* Wv = (const float*)d_in[6];
  const float* bv = (const float*)d_in[7];
  const float* Wo = (const float*)d_in[8];
  const float* bo = (const float*)d_in[9];

  const size_t NE = (size_t)B_ * S_ * D_;  // 4194304
  short* ws_s = (short*)d_ws;
  short* q_ws = ws_s;             // [B,H,S,DH] bf16 row-major (8 MB)
  short* KF = ws_s + NE;          // K fragment-order (8 MB)
  short* VF = ws_s + 2 * NE;      // V fragment-order, PV-permuted (8 MB)
  short* ctx_ws = ws_s + 3 * NE;  // [B,S,D] bf16 row-major (8 MB)
  short* wo_bf = ws_s;            // Wo bf16 (2 MB) -- aliases q_ws, written
                                  // only after attn (q_ws dead then)
  // scratch inside d_out (all dead before the final GEMM runs):
  short* qbf = (short*)d_out;          // [0:8M)  query bf16, fragment order
  short* wqkv = qbf + NE;              // [8:14M) Wq|Wk|Wv bf16, fragment order
  uint* bmT = (uint*)(wqkv + 3145728); // [14:15M) bitmask

  prep_kernel<<<4608, 256, 0, stream>>>(query, Wq, Wk, Wv, mask, qbf, wqkv,
                                        bmT);

  gemm_qkv_kernel<<<dim3(32, 24), 256, 0, stream>>>(qbf, wqkv, bq, bk, bv,
                                                    q_ws, KF, VF);

  attn_kernel<<<512, 512, 0, stream>>>(q_ws, KF, VF, bmT, ctx_ws);

  convert_wo_kernel<<<512, 256, 0, stream>>>(Wo, wo_bf);

  gemm_final_kernel<<<512, 256, 0, stream>>>(ctx_ws, wo_bf, bo, (float*)d_out);
}